// Round 3
// baseline (245.295 us; speedup 1.0000x reference)
//
#include <hip/hip_runtime.h>

#define NB  2
#define NH  12
#define NQ  2048
#define NKV 2048
#define DH  64
#define KVB 64

typedef __attribute__((ext_vector_type(8))) short bf16x8;
typedef __attribute__((ext_vector_type(4))) float f32x4;

__device__ __forceinline__ unsigned short f2bf(float f) {
    unsigned int u = __float_as_uint(f);
    u += 0x7FFFu + ((u >> 16) & 1u);          // round-to-nearest-even
    return (unsigned short)(u >> 16);
}

// LDS arena (bytes):
//   [0,     8448)  bias_s : f32[2112]                (whole kernel)
//   [8448, 17664)  Ks     : u16[64][72]              (kv loop)   | merge: mO f32[4][16][68] (17408 B)
//   [17664,26880)  Vs     : u16[64][72]              (kv loop)   |        + m/l f32[128]    (512 B)
//   [26880,37120)  Ps     : u16[8][16][40]           (kv loop)
#define ARENA_BYTES 37120

__global__ __launch_bounds__(512, 6)
void attn_fwd(const float* __restrict__ Q, const float* __restrict__ K,
              const float* __restrict__ V, const float* __restrict__ M,
              const float* __restrict__ Bias, float* __restrict__ O)
{
    const int tid  = threadIdx.x;
    const int w    = tid >> 6;      // wave 0..7
    const int wq   = w >> 1;        // q-wave: owns q-rows [wq*16, wq*16+16)
    const int wk   = w & 1;         // kv-half: owns kv [wk*32, wk*32+32) of each tile
    const int lane = tid & 63;
    const int l16  = lane & 15;
    const int g    = lane >> 4;

    const int qt = blockIdx.x & 31;            // 32 q-tiles of 64
    const int h  = (blockIdx.x >> 5) % NH;
    const int b  = blockIdx.x / (32 * NH);
    const int q0 = qt * 64;

    __shared__ __align__(16) char arena[ARENA_BYTES];
    float* bias_s = (float*)arena;
    unsigned short (*Ks)[72]     = (unsigned short(*)[72])(arena + 8448);
    unsigned short (*Vs)[72]     = (unsigned short(*)[72])(arena + 17664);
    unsigned short (*Ps)[16][40] = (unsigned short(*)[16][40])(arena + 26880);

    // ---- stage bias band: bias_s[i] = Bias[(q0+1+i)*NH + h]
    for (int i = tid; i < 2112; i += 512)
        bias_s[i] = Bias[(size_t)(q0 + 1 + i) * NH + h];

    // ---- Q fragments (A-frag: row = l16, k = g*8 + j), d split into two K=32 chunks
    const float* qptr = Q + (((size_t)b * NH + h) * NQ + q0 + wq * 16 + l16) * DH;
    bf16x8 qa[2];
#pragma unroll
    for (int dc = 0; dc < 2; ++dc) {
        const float4 f0 = *(const float4*)(qptr + dc * 32 + g * 8);
        const float4 f1 = *(const float4*)(qptr + dc * 32 + g * 8 + 4);
        qa[dc][0] = (short)f2bf(f0.x); qa[dc][1] = (short)f2bf(f0.y);
        qa[dc][2] = (short)f2bf(f0.z); qa[dc][3] = (short)f2bf(f0.w);
        qa[dc][4] = (short)f2bf(f1.x); qa[dc][5] = (short)f2bf(f1.y);
        qa[dc][6] = (short)f2bf(f1.z); qa[dc][7] = (short)f2bf(f1.w);
    }

    f32x4 o[4];
#pragma unroll
    for (int nt = 0; nt < 4; ++nt) { o[nt][0]=0.f; o[nt][1]=0.f; o[nt][2]=0.f; o[nt][3]=0.f; }
    float m_r[4] = {-1e30f, -1e30f, -1e30f, -1e30f};
    float l_r[4] = {0.f, 0.f, 0.f, 0.f};

    const float* kbase = K + ((size_t)b * NH + h) * NKV * DH;
    const float* vbase = V + ((size_t)b * NH + h) * NKV * DH;
    // per-lane mask row ptrs: mask[b][0][q0+wq*16+g*4+r][wk*32 + l16 + ...]
    const float* mrow[4];
#pragma unroll
    for (int r = 0; r < 4; ++r)
        mrow[r] = M + (size_t)b * NQ * NKV
                    + (size_t)(q0 + wq * 16 + g * 4 + r) * NKV + wk * 32 + l16;

    // staging mapping: 64x64 tile, 512 threads: rows i*32+r0, cols c0..c0+3
    const int r0 = tid >> 4, c0 = (tid & 15) * 4;

    // ---- prologue: issue tile-0 loads into registers
    float4 kr[2], vr[2];
    float  mr[4][2];
#pragma unroll
    for (int i = 0; i < 2; ++i)
        kr[i] = *(const float4*)(kbase + (size_t)(i * 32 + r0) * DH + c0);
#pragma unroll
    for (int i = 0; i < 2; ++i)
        vr[i] = *(const float4*)(vbase + (size_t)(i * 32 + r0) * DH + c0);
#pragma unroll
    for (int r = 0; r < 4; ++r)
#pragma unroll
        for (int nt = 0; nt < 2; ++nt) mr[r][nt] = mrow[r][nt * 16];

    for (int t = 0; t < NKV / KVB; ++t) {
        const int kv0 = t * KVB;
        const int kvn = ((t + 1) & (NKV / KVB - 1)) * KVB;  // wraps on last iter

        __syncthreads();   // all waves done reading previous LDS tile
        // ---- staged registers -> LDS (convert to bf16)
#pragma unroll
        for (int i = 0; i < 2; ++i) {
            unsigned short* dst = &Ks[i * 32 + r0][c0];
            dst[0] = f2bf(kr[i].x); dst[1] = f2bf(kr[i].y);
            dst[2] = f2bf(kr[i].z); dst[3] = f2bf(kr[i].w);
        }
#pragma unroll
        for (int i = 0; i < 2; ++i) {
            const int rr = i * 32 + r0;
            Vs[c0 + 0][rr] = f2bf(vr[i].x); Vs[c0 + 1][rr] = f2bf(vr[i].y);
            Vs[c0 + 2][rr] = f2bf(vr[i].z); Vs[c0 + 3][rr] = f2bf(vr[i].w);
        }
        // ---- issue next-tile K/V loads (hide under compute)
#pragma unroll
        for (int i = 0; i < 2; ++i)
            kr[i] = *(const float4*)(kbase + (size_t)(kvn + i * 32 + r0) * DH + c0);
#pragma unroll
        for (int i = 0; i < 2; ++i)
            vr[i] = *(const float4*)(vbase + (size_t)(kvn + i * 32 + r0) * DH + c0);
        __syncthreads();   // LDS tile ready

        // ---- S = Q K^T for this wave's 16q x 32kv slice
        f32x4 s[2];
#pragma unroll
        for (int nt = 0; nt < 2; ++nt) {
            f32x4 acc; acc[0]=0.f; acc[1]=0.f; acc[2]=0.f; acc[3]=0.f;
            const int kvrow = wk * 32 + nt * 16 + l16;
            const bf16x8 kb0 = *(const bf16x8*)(&Ks[kvrow][g * 8]);
            const bf16x8 kb1 = *(const bf16x8*)(&Ks[kvrow][32 + g * 8]);
            acc = __builtin_amdgcn_mfma_f32_16x16x32_bf16(qa[0], kb0, acc, 0, 0, 0);
            acc = __builtin_amdgcn_mfma_f32_16x16x32_bf16(qa[1], kb1, acc, 0, 0, 0);
            s[nt] = acc;
        }

        // ---- scale + bias + mask, online softmax (row = wq*16 + g*4 + r)
#pragma unroll
        for (int r = 0; r < 4; ++r) {
            const int qr = wq * 16 + g * 4 + r;
#pragma unroll
            for (int nt = 0; nt < 2; ++nt) {
                const int kk = kv0 + wk * 32 + nt * 16 + l16;
                float x = s[nt][r] * 0.125f + mr[r][nt];
                x += bias_s[qr - kk + 2047];
                s[nt][r] = x;
            }
            float mx = fmaxf(s[0][r], s[1][r]);
            mx = fmaxf(mx, __shfl_xor(mx, 1));
            mx = fmaxf(mx, __shfl_xor(mx, 2));
            mx = fmaxf(mx, __shfl_xor(mx, 4));
            mx = fmaxf(mx, __shfl_xor(mx, 8));
            const float mo = m_r[r];
            const float mn = fmaxf(mo, mx);
            m_r[r] = mn;
            const float alpha = __expf(mo - mn);
            const float p0 = __expf(s[0][r] - mn);
            const float p1 = __expf(s[1][r] - mn);
            float rs = p0 + p1;
            rs += __shfl_xor(rs, 1);
            rs += __shfl_xor(rs, 2);
            rs += __shfl_xor(rs, 4);
            rs += __shfl_xor(rs, 8);
            l_r[r] = l_r[r] * alpha + rs;
#pragma unroll
            for (int nt = 0; nt < 4; ++nt) o[nt][r] *= alpha;
            Ps[w][g * 4 + r][l16]      = f2bf(p0);
            Ps[w][g * 4 + r][16 + l16] = f2bf(p1);
        }

        // ---- issue next-tile mask loads
#pragma unroll
        for (int r = 0; r < 4; ++r)
#pragma unroll
            for (int nt = 0; nt < 2; ++nt) mr[r][nt] = mrow[r][kvn + nt * 16];

        // ---- PV: A = P (16x32 slice), B^T = V^T rows at kv = wk*32 + g*8
        const bf16x8 pa = *(const bf16x8*)(&Ps[w][l16][g * 8]);
#pragma unroll
        for (int nt = 0; nt < 4; ++nt) {
            const bf16x8 vb = *(const bf16x8*)(&Vs[nt * 16 + l16][wk * 32 + g * 8]);
            o[nt] = __builtin_amdgcn_mfma_f32_16x16x32_bf16(pa, vb, o[nt], 0, 0, 0);
        }
    }

    // ==== merge the two kv-halves (wk=0 <- wk=1) through LDS ====
    __syncthreads();   // kv loop done; Ks/Vs/Ps regions now reusable
    float (*mO)[16][68] = (float(*)[16][68])(arena + 8448);   // 17408 B
    float* mML          = (float*)(arena + 8448 + 17408);     // m[64] | l[64]

    if (wk == 1) {
#pragma unroll
        for (int r = 0; r < 4; ++r) {
#pragma unroll
            for (int nt = 0; nt < 4; ++nt)
                mO[wq][g * 4 + r][nt * 16 + l16] = o[nt][r];
            if (l16 == 0) {
                mML[wq * 16 + g * 4 + r]      = m_r[r];
                mML[64 + wq * 16 + g * 4 + r] = l_r[r];
            }
        }
    }
    __syncthreads();
    if (wk == 0) {
        float* obase = O + (((size_t)b * NH + h) * NQ + q0 + wq * 16) * DH;
#pragma unroll
        for (int r = 0; r < 4; ++r) {
            const int row = g * 4 + r;
            const float m1 = mML[wq * 16 + row];
            const float l1 = mML[64 + wq * 16 + row];
            const float mn = fmaxf(m_r[r], m1);
            const float a0 = __expf(m_r[r] - mn);
            const float a1 = __expf(m1 - mn);
            const float inv = 1.f / (l_r[r] * a0 + l1 * a1);
#pragma unroll
            for (int nt = 0; nt < 4; ++nt)
                obase[(size_t)row * DH + nt * 16 + l16] =
                    (o[nt][r] * a0 + mO[wq][row][nt * 16 + l16] * a1) * inv;
        }
    }
}

extern "C" void kernel_launch(void* const* d_in, const int* in_sizes, int n_in,
                              void* d_out, int out_size, void* d_ws, size_t ws_size,
                              hipStream_t stream) {
    const float* Q    = (const float*)d_in[0];
    const float* K    = (const float*)d_in[1];
    const float* V    = (const float*)d_in[2];
    const float* M    = (const float*)d_in[3];
    const float* Bias = (const float*)d_in[4];
    float* O = (float*)d_out;

    dim3 grid(NB * NH * (NQ / 64));   // 768 blocks = 3/CU, 8 waves each
    dim3 block(512);
    attn_fwd<<<grid, block, 0, stream>>>(Q, K, V, M, Bias, O);
}